// Round 15
// baseline (329.148 us; speedup 1.0000x reference)
//
#include <hip/hip_runtime.h>

#define NN 100000
#define EE 640000

typedef float f32x4 __attribute__((ext_vector_type(4)));
typedef __bf16 bf16x8 __attribute__((ext_vector_type(8)));
typedef unsigned short u16x4 __attribute__((ext_vector_type(4)));
typedef unsigned short u16x8 __attribute__((ext_vector_type(8)));

__device__ __forceinline__ unsigned short f2b(float f) {
  unsigned u = __float_as_uint(f);
  u += 0x7fffu + ((u >> 16) & 1u);   // RNE; inputs finite
  return (unsigned short)(u >> 16);
}
__device__ __forceinline__ float b2f(unsigned short h) {
  return __uint_as_float(((unsigned)h) << 16);
}
__device__ __forceinline__ void gl2lds(const void* g, void* l) {
  __builtin_amdgcn_global_load_lds((const __attribute__((address_space(1))) void*)g,
                                   (__attribute__((address_space(3))) void*)l, 16, 0, 0);
}

// ---------- weights: transpose + XOR-swizzle + bf16 (7 chunks of 128x128) ----------
__global__ __launch_bounds__(256) void prep_wt(
    const float* __restrict__ w0, const float* __restrict__ w1,
    const float* __restrict__ w2, const float* __restrict__ w3,
    const float* __restrict__ w4, const float* __restrict__ w5,
    unsigned short* __restrict__ wt) {
  int chunk = blockIdx.x >> 4, sub = blockIdx.x & 15;
  const float* W; int kc = 0;
  switch (chunk) {
    case 0: W = w0; break;
    case 1: W = w1; break;
    case 2: W = w2; break;
    case 3: W = w3; break;
    case 4: W = w4; break;
    case 5: W = w4; kc = 128; break;
    default: W = w5; break;
  }
  unsigned short* out = wt + chunk * 16384;
#pragma unroll
  for (int p = 0; p < 4; ++p) {
    int idx = sub * 1024 + p * 256 + threadIdx.x;
    int k = idx >> 7, c = idx & 127;
    out[c * 128 + (((k >> 3) ^ (c & 7)) << 3) + (k & 7)] = f2b(W[(kc + k) * 128 + c]);
  }
}

// ---------- shared device pieces ----------
__device__ __forceinline__ void mfma_128(const unsigned short* __restrict__ Alds,
                                         const unsigned short* __restrict__ wsrc,
                                         int wm, int wn, int lane, f32x4 (&acc)[2][4]) {
#pragma unroll
  for (int ks = 0; ks < 4; ++ks) {
    const int kg = ks * 4 + (lane >> 4);
    bf16x8 af[2], bfr[4];
#pragma unroll
    for (int m = 0; m < 2; ++m) {
      int rr = wm + m * 16 + (lane & 15);
      af[m] = *(const bf16x8*)&Alds[rr * 128 + ((kg ^ (rr & 7)) << 3)];
    }
#pragma unroll
    for (int n = 0; n < 4; ++n) {
      int cc = wn + n * 16 + (lane & 15);
      bfr[n] = *(const bf16x8*)(wsrc + cc * 128 + ((kg ^ (cc & 7)) << 3));
    }
#pragma unroll
    for (int m = 0; m < 2; ++m)
#pragma unroll
      for (int n = 0; n < 4; ++n)
        acc[m][n] = __builtin_amdgcn_mfma_f32_16x16x32_bf16(bfr[n], af[m], acc[m][n], 0, 0, 0);
  }
}
// NOTE: operands swapped above -> acc holds C^T: lane owns row (lane&15), cols (lane>>4)*4+i

__device__ __forceinline__ void stats_to_lds(const f32x4 (&acc)[2][4], float* __restrict__ Sred,
                                             int wid, int wn, int lane) {
  // C^T frags: col c = wn + n*16 + (lane>>4)*4 + i ; rows = m, lane&15
  float s[4] = {0.f, 0.f, 0.f, 0.f}, q[4] = {0.f, 0.f, 0.f, 0.f};
#pragma unroll
  for (int n = 0; n < 4; ++n)
#pragma unroll
    for (int m = 0; m < 2; ++m)
#pragma unroll
      for (int i = 0; i < 4; ++i) {
        float v = acc[m][n][i];
        s[n] += (i == 0) ? v : 0.f;   // placeholder (restructured below)
        q[n] += 0.f;
      }
  // proper: per (n,i) column partial, reduce over lane&15
  f32x4 sv[4], qv[4];
#pragma unroll
  for (int n = 0; n < 4; ++n) {
#pragma unroll
    for (int i = 0; i < 4; ++i) {
      float v0 = acc[0][n][i], v1 = acc[1][n][i];
      sv[n][i] = v0 + v1;
      qv[n][i] = v0 * v0 + v1 * v1;
    }
#pragma unroll
    for (int d = 1; d < 16; d <<= 1) {
#pragma unroll
      for (int i = 0; i < 4; ++i) {
        sv[n][i] += __shfl_xor(sv[n][i], d);
        qv[n][i] += __shfl_xor(qv[n][i], d);
      }
    }
  }
  const int mg = wid >> 1, cg = lane >> 4;
  if ((lane & 15) == 0) {
#pragma unroll
    for (int n = 0; n < 4; ++n) {
      *(f32x4*)&Sred[mg * 128 + wn + n * 16 + cg * 4] = sv[n];
      *(f32x4*)&Sred[512 + mg * 128 + wn + n * 16 + cg * 4] = qv[n];
    }
  }
}

// write C^T frags into Alds (A-tile dead), swizzled like staging
__device__ __forceinline__ void ct_to_lds(const f32x4 (&acc)[2][4], unsigned short* __restrict__ Alds,
                                          int wm, int wn, int lane) {
  const int cg = lane >> 4;
#pragma unroll
  for (int m = 0; m < 2; ++m) {
    int r = wm + m * 16 + (lane & 15);
#pragma unroll
    for (int n = 0; n < 4; ++n) {
      int col = wn + n * 16 + cg * 4;
      u16x4 p;
      p.x = f2b(acc[m][n][0]); p.y = f2b(acc[m][n][1]);
      p.z = f2b(acc[m][n][2]); p.w = f2b(acc[m][n][3]);
      *(u16x4*)&Alds[r * 128 + (((col >> 3) ^ (r & 7)) << 3) + (col & 7)] = p;
    }
  }
}

// coalesced 256-B row stores from Alds
__device__ __forceinline__ void rows_out(const unsigned short* __restrict__ Alds,
                                         int row0, int tid, unsigned short* __restrict__ H) {
  const int uu = tid & 15;
#pragma unroll
  for (int it = 0; it < 4; ++it) {
    int r = it * 32 + (tid >> 4);
    int R = row0 + r;
    u16x8 v = *(const u16x8*)&Alds[r * 128 + ((uu ^ (r & 7)) << 3)];
    if (R < NN) *(u16x8*)&H[(size_t)R * 128 + uu * 8] = v;
  }
}

// ---------- G1: dual-output GEMM — one feat read, two layers (L1, L3) ----------
__global__ __launch_bounds__(512, 4) void gemm_dual(
    const float* __restrict__ feat, const unsigned short* __restrict__ W0,
    const unsigned short* __restrict__ W2, unsigned short* __restrict__ H1,
    unsigned short* __restrict__ H3, float* __restrict__ cs0, float* __restrict__ cq0,
    float* __restrict__ cs2, float* __restrict__ cq2) {
  __shared__ unsigned short Alds[16384];
  __shared__ float Sred[1024];
  const int tid = threadIdx.x;
  const int lane = tid & 63, wid = tid >> 6;
  const int row0 = blockIdx.x * 128;
  const int wm = (wid >> 1) * 32, wn = (wid & 1) * 64;
  const int kq = (tid & 31) * 4;
  const int rbase = tid >> 5;
  {
    f32x4 raw[8];
    const f32x4 zz = {};
#pragma unroll
    for (int it = 0; it < 8; ++it) {
      int grow = row0 + it * 16 + rbase;
      raw[it] = (grow < NN) ? *(const f32x4*)(feat + (size_t)grow * 128 + kq) : zz;
    }
#pragma unroll
    for (int it = 0; it < 8; ++it) {
      int r = it * 16 + rbase;
      u16x4 p;
      p.x = f2b(raw[it].x); p.y = f2b(raw[it].y);
      p.z = f2b(raw[it].z); p.w = f2b(raw[it].w);
      *(u16x4*)&Alds[r * 128 + (((kq >> 3) ^ (r & 7)) << 3) + (kq & 7)] = p;
    }
  }
  __syncthreads();
  f32x4 accA[2][4] = {}, accB[2][4] = {};
  mfma_128(Alds, W0, wm, wn, lane, accA);
  mfma_128(Alds, W2, wm, wn, lane, accB);
  stats_to_lds(accA, Sred, wid, wn, lane);
  __syncthreads();                 // MFMA reads of Alds done; Sred written
  ct_to_lds(accA, Alds, wm, wn, lane);
  __syncthreads();
  rows_out(Alds, row0, tid, H1);
  if (tid < 256) {
    int col = tid & 127;
    const float* sp = &Sred[(tid < 128) ? 0 : 512];
    float v = sp[col] + sp[128 + col] + sp[256 + col] + sp[384 + col];
    unsafeAtomicAdd(((tid < 128) ? cs0 : cq0) + col, v);
  }
  __syncthreads();                 // Sred/Alds reads done
  stats_to_lds(accB, Sred, wid, wn, lane);
  ct_to_lds(accB, Alds, wm, wn, lane);
  __syncthreads();
  rows_out(Alds, row0, tid, H3);
  if (tid < 256) {
    int col = tid & 127;
    const float* sp = &Sred[(tid < 128) ? 0 : 512];
    float v = sp[col] + sp[128 + col] + sp[256 + col] + sp[384 + col];
    unsafeAtomicAdd(((tid < 128) ? cs2 : cq2) + col, v);
  }
}

// ---------- unified GEMM: 512 thr, Alds-reuse epilogue, 3 blocks/CU ----------
// MODE 1: A = bf16 row-major, transform relu(h*sc+sh); sc/sh from raw stats inline
// MODE 2: NCHK=2: ch0 = MODE1 transform on A; ch1 = swizzled bf16 (A2sw) via gl2lds
struct GArg {
  const void* A;
  const unsigned short* A2sw;
  const float* cs; const float* cq; const float* g; const float* be;
  const unsigned short* W;
  unsigned short* H;
  float* ocs; float* ocq;
};

template <int NCHK, int MODE>
__global__ __launch_bounds__(512, 6) void gemm_bn(GArg pa, GArg pb) {
  const GArg P = blockIdx.y ? pb : pa;
  __shared__ unsigned short Alds[16384];    // 32 KB A tile, reused for epilogue
  __shared__ float Sred[1024];              // 4 KB stats partials
  __shared__ float scs[128], shs[128];

  const int tid = threadIdx.x;
  if (tid < 128) {
    float mu = P.cs[tid] * (1.f / NN);
    float var = P.cq[tid] * (1.f / NN) - mu * mu;
    float s = P.g[tid] * rsqrtf(fmaxf(var, 0.f) + 1e-5f);
    scs[tid] = s;
    shs[tid] = P.be[tid] - mu * s;
  }
  __syncthreads();
  const int lane = tid & 63, wid = tid >> 6;
  const int row0 = blockIdx.x * 128;
  const int wm = (wid >> 1) * 32, wn = (wid & 1) * 64;
  const int kq = (tid & 31) * 4;
  const int rbase = tid >> 5;
  const f32x4 scv = *(const f32x4*)&scs[kq];
  const f32x4 shv = *(const f32x4*)&shs[kq];

  f32x4 acc[2][4] = {};
#pragma unroll
  for (int ch = 0; ch < NCHK; ++ch) {
    if (ch) __syncthreads();
    if (MODE == 2 && ch == 1) {
#pragma unroll
      for (int j = 0; j < 4; ++j) {
        int u = (wid * 4 + j) * 64 + lane;
        gl2lds(P.A2sw + (size_t)blockIdx.x * 16384 + (size_t)u * 8,
               &Alds[(wid * 4 + j) * 512]);
      }
    } else {
      u16x4 raw[8];
      const u16x4 zz = {};
#pragma unroll
      for (int it = 0; it < 8; ++it) {
        int grow = row0 + it * 16 + rbase;
        raw[it] = (grow < NN) ? *(const u16x4*)((const unsigned short*)P.A + (size_t)grow * 128 + kq)
                              : zz;
      }
#pragma unroll
      for (int it = 0; it < 8; ++it) {
        int r = it * 16 + rbase;
        bool ok = (row0 + r) < NN;
        float v0 = fmaxf(b2f(raw[it].x) * scv.x + shv.x, 0.f);
        float v1 = fmaxf(b2f(raw[it].y) * scv.y + shv.y, 0.f);
        float v2 = fmaxf(b2f(raw[it].z) * scv.z + shv.z, 0.f);
        float v3 = fmaxf(b2f(raw[it].w) * scv.w + shv.w, 0.f);
        u16x4 p;
        p.x = ok ? f2b(v0) : (unsigned short)0;
        p.y = ok ? f2b(v1) : (unsigned short)0;
        p.z = ok ? f2b(v2) : (unsigned short)0;
        p.w = ok ? f2b(v3) : (unsigned short)0;
        *(u16x4*)&Alds[r * 128 + (((kq >> 3) ^ (r & 7)) << 3) + (kq & 7)] = p;
      }
    }
    __syncthreads();
    mfma_128(Alds, P.W + ch * 16384, wm, wn, lane, acc);
  }
  stats_to_lds(acc, Sred, wid, wn, lane);
  __syncthreads();                 // all MFMA reads of Alds done
  ct_to_lds(acc, Alds, wm, wn, lane);
  __syncthreads();
  rows_out(Alds, row0, tid, P.H);
  if (tid < 256) {
    int col = tid & 127;
    const float* sp = &Sred[(tid < 128) ? 0 : 512];
    float v = sp[col] + sp[128 + col] + sp[256 + col] + sp[384 + col];
    unsafeAtomicAdd(((tid < 128) ? P.ocs : P.ocq) + col, v);
  }
}

// ---------- CSR build: histogram, unordered block allocation, edge-id scatter ----------
__global__ __launch_bounds__(256) void hist_slot(const int* __restrict__ dst,
                                                 int* __restrict__ deg, int* __restrict__ slot) {
  int e = blockIdx.x * 256 + threadIdx.x;
  if (e < EE) slot[e] = atomicAdd(&deg[dst[e]], 1);
}

__global__ __launch_bounds__(256) void alloc_rows(const int* __restrict__ deg,
                                                  int* __restrict__ counter,
                                                  int* __restrict__ row_ptr) {
  __shared__ int tmp[256];
  __shared__ int base_s;
  int i = blockIdx.x * 256 + threadIdx.x;
  int t = threadIdx.x;
  int v = (i < NN) ? deg[i] : 0;
  tmp[t] = v;
  __syncthreads();
  for (int s = 1; s < 256; s <<= 1) {
    int a = (t >= s) ? tmp[t - s] : 0;
    __syncthreads();
    tmp[t] += a;
    __syncthreads();
  }
  if (t == 255) base_s = atomicAdd(counter, tmp[255]);
  __syncthreads();
  if (i < NN) row_ptr[i] = base_s + tmp[t] - v;
}

__global__ __launch_bounds__(256) void scatter_ids(const int* __restrict__ src,
                                                   const int* __restrict__ dst,
                                                   const int* __restrict__ row_ptr,
                                                   const int* __restrict__ slot,
                                                   int* __restrict__ csr_src) {
  int e = blockIdx.x * 256 + threadIdx.x;
  if (e < EE) csr_src[row_ptr[dst[e]] + slot[e]] = src[e];
}

// ---------- gather + mean: scalarized CSR walk, 8-deep pipeline ----------
__global__ __launch_bounds__(256) void gather_mean(
    const unsigned short* __restrict__ h2, const float* __restrict__ csIn,
    const float* __restrict__ cqIn, const float* __restrict__ g,
    const float* __restrict__ beta, const int* __restrict__ csr_src,
    const int* __restrict__ row_ptr, const int* __restrict__ deg,
    unsigned short* __restrict__ mean_sw) {
  const int lane = threadIdx.x & 63;
  const int node = (blockIdx.x << 2) + (threadIdx.x >> 6);
  if (node >= 100096) return;
  const int c0 = lane * 2;
  float mu0 = csIn[c0] * (1.f / NN), mu1 = csIn[c0 + 1] * (1.f / NN);
  float va0 = cqIn[c0] * (1.f / NN) - mu0 * mu0, va1 = cqIn[c0 + 1] * (1.f / NN) - mu1 * mu1;
  float s0 = g[c0] * rsqrtf(fmaxf(va0, 0.f) + 1e-5f);
  float s1 = g[c0 + 1] * rsqrtf(fmaxf(va1, 0.f) + 1e-5f);
  float t0 = beta[c0] - mu0 * s0, t1 = beta[c0 + 1] - mu1 * s1;
  float a0 = 0.f, a1 = 0.f, rc = 0.f;
  if (node < NN) {
    const int beg = __builtin_amdgcn_readfirstlane(row_ptr[node]);
    const int d = __builtin_amdgcn_readfirstlane(deg[node]);
    const int end = beg + d;
    int e = beg;
    for (; e + 8 <= end; e += 8) {
      int ix[8];
#pragma unroll
      for (int k = 0; k < 8; ++k) ix[k] = csr_src[e + k];
      unsigned u[8];
#pragma unroll
      for (int k = 0; k < 8; ++k) u[k] = *(const unsigned*)(h2 + (size_t)ix[k] * 128 + c0);
#pragma unroll
      for (int k = 0; k < 8; ++k) {
        a0 += fmaxf(b2f((unsigned short)u[k]) * s0 + t0, 0.f);
        a1 += fmaxf(b2f((unsigned short)(u[k] >> 16)) * s1 + t1, 0.f);
      }
    }
    if (e + 4 <= end) {
      int ix[4];
#pragma unroll
      for (int k = 0; k < 4; ++k) ix[k] = csr_src[e + k];
      unsigned u[4];
#pragma unroll
      for (int k = 0; k < 4; ++k) u[k] = *(const unsigned*)(h2 + (size_t)ix[k] * 128 + c0);
#pragma unroll
      for (int k = 0; k < 4; ++k) {
        a0 += fmaxf(b2f((unsigned short)u[k]) * s0 + t0, 0.f);
        a1 += fmaxf(b2f((unsigned short)(u[k] >> 16)) * s1 + t1, 0.f);
      }
      e += 4;
    }
    if (e + 2 <= end) {
      int n0 = csr_src[e], n1 = csr_src[e + 1];
      unsigned u0 = *(const unsigned*)(h2 + (size_t)n0 * 128 + c0);
      unsigned u1 = *(const unsigned*)(h2 + (size_t)n1 * 128 + c0);
      a0 += fmaxf(b2f((unsigned short)u0) * s0 + t0, 0.f);
      a1 += fmaxf(b2f((unsigned short)(u0 >> 16)) * s1 + t1, 0.f);
      a0 += fmaxf(b2f((unsigned short)u1) * s0 + t0, 0.f);
      a1 += fmaxf(b2f((unsigned short)(u1 >> 16)) * s1 + t1, 0.f);
      e += 2;
    }
    if (e < end) {
      int n0 = csr_src[e];
      unsigned u0 = *(const unsigned*)(h2 + (size_t)n0 * 128 + c0);
      a0 += fmaxf(b2f((unsigned short)u0) * s0 + t0, 0.f);
      a1 += fmaxf(b2f((unsigned short)(u0 >> 16)) * s1 + t1, 0.f);
    }
    rc = (d > 0) ? 1.f / (float)d : 0.f;
  }
  // swizzled write matching gl2lds consumption
  int r = node & 127, t = node >> 7;
  int kk = (lane >> 2) ^ (r & 7);
  unsigned out = ((unsigned)f2b(a1 * rc) << 16) | (unsigned)f2b(a0 * rc);
  *(unsigned*)(mean_sw + (size_t)(t * 2048 + r * 16 + kk) * 8 + (lane & 3) * 2) = out;
}

// ---------- final normalize -> fp32 out (inline stats) ----------
__global__ __launch_bounds__(256) void norm_out(
    const unsigned short* __restrict__ h, const float* __restrict__ csIn,
    const float* __restrict__ cqIn, const float* __restrict__ g,
    const float* __restrict__ beta, float* __restrict__ out) {
  __shared__ float scs[128], shs[128];
  const int tid = threadIdx.x;
  if (tid < 128) {
    float mu = csIn[tid] * (1.f / NN);
    float var = cqIn[tid] * (1.f / NN) - mu * mu;
    float s = g[tid] * rsqrtf(fmaxf(var, 0.f) + 1e-5f);
    scs[tid] = s;
    shs[tid] = beta[tid] - mu * s;
  }
  __syncthreads();
  size_t e = ((size_t)blockIdx.x * 256 + tid) * 8;
  u16x8 v = *(const u16x8*)(h + e);
  int cb = (int)(e & 127);
  f32x4 sA = *(const f32x4*)&scs[cb], sB = *(const f32x4*)&scs[cb + 4];
  f32x4 tA = *(const f32x4*)&shs[cb], tB = *(const f32x4*)&shs[cb + 4];
  f32x4 o0, o1;
  o0.x = fmaxf(b2f(v[0]) * sA.x + tA.x, 0.f);
  o0.y = fmaxf(b2f(v[1]) * sA.y + tA.y, 0.f);
  o0.z = fmaxf(b2f(v[2]) * sA.z + tA.z, 0.f);
  o0.w = fmaxf(b2f(v[3]) * sA.w + tA.w, 0.f);
  o1.x = fmaxf(b2f(v[4]) * sB.x + tB.x, 0.f);
  o1.y = fmaxf(b2f(v[5]) * sB.y + tB.y, 0.f);
  o1.z = fmaxf(b2f(v[6]) * sB.z + tB.z, 0.f);
  o1.w = fmaxf(b2f(v[7]) * sB.w + tB.w, 0.f);
  *(f32x4*)(out + e) = o0;
  *(f32x4*)(out + e + 4) = o1;
}

extern "C" void kernel_launch(void* const* d_in, const int* in_sizes, int n_in,
                              void* d_out, int out_size, void* d_ws, size_t ws_size,
                              hipStream_t stream) {
  (void)in_sizes; (void)n_in; (void)out_size; (void)ws_size;
  const float* feat = (const float*)d_in[0];
  const int* src = (const int*)d_in[1];
  const int* dst = (const int*)d_in[2];
  const float* aW1 = (const float*)d_in[3];
  const float* aW2 = (const float*)d_in[4];
  const float* sW1 = (const float*)d_in[5];
  const float* sW2 = (const float*)d_in[6];
  const float* cW1 = (const float*)d_in[7];
  const float* cW2 = (const float*)d_in[8];
  // layer order: 0=aggr1 1=aggr2 2=self1 3=self2 4=comb1 5=comb2
  const float* g[6] = {(const float*)d_in[10], (const float*)d_in[13],
                       (const float*)d_in[16], (const float*)d_in[19],
                       (const float*)d_in[22], (const float*)d_in[25]};
  const float* be[6] = {(const float*)d_in[11], (const float*)d_in[14],
                        (const float*)d_in[17], (const float*)d_in[20],
                        (const float*)d_in[23], (const float*)d_in[26]};

  char* ws = (char*)d_ws;
  const size_t S = 25624576;                                   // 782 tiles * 32768 B
  unsigned short* WA = (unsigned short*)ws;                    // h1 / mean_sw
  unsigned short* WB = (unsigned short*)(ws + S);              // h2 / h6
  unsigned short* WC = (unsigned short*)(ws + 2 * S);          // h3 / h5
  int* row_ptr = (int*)(ws + 76873728);                        // 400,128 B
  int* deg = (int*)(ws + 77273856);                            // 400,000 B
  float* stats = (float*)(ws + 77673856);                      // 12,288 B (has spare slots)
  int* slot = (int*)(ws + 77686144);                           // 2,560,000 B
  int* csr_src = (int*)(ws + 80248192);                        // 2,560,000 B
  unsigned short* wt = (unsigned short*)(ws + 82808192);       // 229,376 B
  float* outF = (float*)d_out;
  unsigned short* h4 = (unsigned short*)d_out;                 // h4 parked in d_out bytes

  float* CS[6]; float* CQ[6];
  for (int L = 0; L < 6; ++L) {
    CS[L] = stats + L * 512;
    CQ[L] = stats + L * 512 + 128;
  }
  int* counter = (int*)(stats + 256);                          // spare slot, covered by memset

  hipMemsetAsync(deg, 0, 412288, stream);                      // deg + stats (incl. counter)
  prep_wt<<<112, 256, 0, stream>>>(aW1, aW2, sW1, sW2, cW1, cW2, wt);

  // CSR build: histogram -> unordered block allocation -> id scatter
  hist_slot<<<2500, 256, 0, stream>>>(dst, deg, slot);
  alloc_rows<<<391, 256, 0, stream>>>(deg, counter, row_ptr);
  scatter_ids<<<2500, 256, 0, stream>>>(src, dst, row_ptr, slot, csr_src);

  // G1: dual-output — one feat read, L1 -> h1 (WA), L3 -> h3 (WC)
  gemm_dual<<<782, 512, 0, stream>>>(feat, wt + 0 * 16384, wt + 2 * 16384,
                                     WA, WC, CS[0], CQ[0], CS[2], CQ[2]);
  GArg a{}, b{};
  // G2: L2+L4 batched (A = h1 / h3, MODE1)
  a = {WA, nullptr, CS[0], CQ[0], g[0], be[0], wt + 1 * 16384, WB, CS[1], CQ[1]};
  b = {WC, nullptr, CS[2], CQ[2], g[2], be[2], wt + 3 * 16384, h4, CS[3], CQ[3]};
  gemm_bn<1, 1><<<dim3(782, 2), 512, 0, stream>>>(a, b);
  // gather: mean of n(h2[src]) per dst -> WA (swizzled; h1 dead)
  gather_mean<<<25024, 256, 0, stream>>>(WB, CS[1], CQ[1], g[1], be[1],
                                         csr_src, row_ptr, deg, WA);
  // G3: L5 = [n(h4) | mean] -> h5 (WC; h3 dead)
  a = {h4, WA, CS[3], CQ[3], g[3], be[3], wt + 4 * 16384, WC, CS[4], CQ[4]};
  gemm_bn<2, 2><<<dim3(782, 1), 512, 0, stream>>>(a, a);
  // G4: L6 = n(h5) -> h6 (WB; h2 dead)
  a = {WC, nullptr, CS[4], CQ[4], g[4], be[4], wt + 6 * 16384, WB, CS[5], CQ[5]};
  gemm_bn<1, 1><<<dim3(782, 1), 512, 0, stream>>>(a, a);
  // final normalize -> fp32 out
  norm_out<<<6250, 256, 0, stream>>>(WB, CS[5], CQ[5], g[5], be[5], outF);
}

// Round 16
// 260.416 us; speedup vs baseline: 1.2639x; 1.2639x over previous
//
#include <hip/hip_runtime.h>

#define NN 100000
#define EE 640000

typedef float f32x4 __attribute__((ext_vector_type(4)));
typedef __bf16 bf16x8 __attribute__((ext_vector_type(8)));
typedef unsigned short u16x4 __attribute__((ext_vector_type(4)));
typedef unsigned short u16x8 __attribute__((ext_vector_type(8)));

__device__ __forceinline__ unsigned short f2b(float f) {
  unsigned u = __float_as_uint(f);
  u += 0x7fffu + ((u >> 16) & 1u);   // RNE; inputs finite
  return (unsigned short)(u >> 16);
}
__device__ __forceinline__ float b2f(unsigned short h) {
  return __uint_as_float(((unsigned)h) << 16);
}
__device__ __forceinline__ void gl2lds(const void* g, void* l) {
  __builtin_amdgcn_global_load_lds((const __attribute__((address_space(1))) void*)g,
                                   (__attribute__((address_space(3))) void*)l, 16, 0, 0);
}

// ---------- weights: transpose + XOR-swizzle + bf16 (7 chunks of 128x128) ----------
__global__ __launch_bounds__(256) void prep_wt(
    const float* __restrict__ w0, const float* __restrict__ w1,
    const float* __restrict__ w2, const float* __restrict__ w3,
    const float* __restrict__ w4, const float* __restrict__ w5,
    unsigned short* __restrict__ wt) {
  int chunk = blockIdx.x >> 4, sub = blockIdx.x & 15;
  const float* W; int kc = 0;
  switch (chunk) {
    case 0: W = w0; break;
    case 1: W = w1; break;
    case 2: W = w2; break;
    case 3: W = w3; break;
    case 4: W = w4; break;
    case 5: W = w4; kc = 128; break;
    default: W = w5; break;
  }
  unsigned short* out = wt + chunk * 16384;
#pragma unroll
  for (int p = 0; p < 4; ++p) {
    int idx = sub * 1024 + p * 256 + threadIdx.x;
    int k = idx >> 7, c = idx & 127;
    out[c * 128 + (((k >> 3) ^ (c & 7)) << 3) + (k & 7)] = f2b(W[(kc + k) * 128 + c]);
  }
}

// ---------- shared device pieces (r12-proven) ----------
__device__ __forceinline__ void mfma_128(const unsigned short* __restrict__ Alds,
                                         const unsigned short* __restrict__ wsrc,
                                         int wm, int wn, int lane, f32x4 (&acc)[2][4]) {
#pragma unroll
  for (int ks = 0; ks < 4; ++ks) {
    const int kg = ks * 4 + (lane >> 4);
    bf16x8 af[2], bfr[4];
#pragma unroll
    for (int m = 0; m < 2; ++m) {
      int rr = wm + m * 16 + (lane & 15);
      af[m] = *(const bf16x8*)&Alds[rr * 128 + ((kg ^ (rr & 7)) << 3)];
    }
#pragma unroll
    for (int n = 0; n < 4; ++n) {
      int cc = wn + n * 16 + (lane & 15);
      bfr[n] = *(const bf16x8*)(wsrc + cc * 128 + ((kg ^ (cc & 7)) << 3));
    }
#pragma unroll
    for (int m = 0; m < 2; ++m)
#pragma unroll
      for (int n = 0; n < 4; ++n)
        acc[m][n] = __builtin_amdgcn_mfma_f32_16x16x32_bf16(af[m], bfr[n], acc[m][n], 0, 0, 0);
  }
}

__device__ __forceinline__ void stats_to_lds(const f32x4 (&acc)[2][4], float* __restrict__ Sred,
                                             int wid, int wn, int lane) {
  float s[4] = {0.f, 0.f, 0.f, 0.f}, q[4] = {0.f, 0.f, 0.f, 0.f};
#pragma unroll
  for (int n = 0; n < 4; ++n)
#pragma unroll
    for (int m = 0; m < 2; ++m)
#pragma unroll
      for (int i = 0; i < 4; ++i) {
        float v = acc[m][n][i];
        s[n] += v;
        q[n] += v * v;
      }
#pragma unroll
  for (int n = 0; n < 4; ++n) {
    s[n] += __shfl_xor(s[n], 16);
    s[n] += __shfl_xor(s[n], 32);
    q[n] += __shfl_xor(q[n], 16);
    q[n] += __shfl_xor(q[n], 32);
  }
  if ((lane >> 4) == 0) {
    int mg = wid >> 1;
#pragma unroll
    for (int n = 0; n < 4; ++n) {
      Sred[mg * 128 + wn + n * 16 + lane] = s[n];
      Sred[512 + mg * 128 + wn + n * 16 + lane] = q[n];
    }
  }
}

__device__ __forceinline__ void epi_store(const f32x4 (&acc)[2][4], unsigned short* __restrict__ ep,
                                          int row0, int wm, int wn, int lane,
                                          unsigned short* __restrict__ H) {
#pragma unroll
  for (int m = 0; m < 2; ++m)
#pragma unroll
    for (int n = 0; n < 4; ++n)
#pragma unroll
      for (int i = 0; i < 4; ++i) {
        int wrow = m * 16 + (lane >> 4) * 4 + i;
        ep[wrow * 80 + n * 16 + (lane & 15)] = f2b(acc[m][n][i]);
      }
#pragma unroll
  for (int i4 = 0; i4 < 4; ++i4) {
    int wrow = i4 * 8 + (lane >> 3);
    u16x8 v = *(const u16x8*)&ep[wrow * 80 + (lane & 7) * 8];
    int R = row0 + wm + wrow;
    if (R < NN) *(u16x8*)&H[(size_t)R * 128 + wn + (lane & 7) * 8] = v;
  }
}

// ---------- G1: dual-output GEMM — one feat read, two layers (L1, L3) ----------
__global__ __launch_bounds__(512, 4) void gemm_dual(
    const float* __restrict__ feat, const unsigned short* __restrict__ W0,
    const unsigned short* __restrict__ W2, unsigned short* __restrict__ H1,
    unsigned short* __restrict__ H3, float* __restrict__ cs0, float* __restrict__ cq0,
    float* __restrict__ cs2, float* __restrict__ cq2) {
  __shared__ unsigned short Alds[16384];
  __shared__ unsigned short Epi[20480];
  __shared__ float Sred[1024];
  const int tid = threadIdx.x;
  const int lane = tid & 63, wid = tid >> 6;
  const int row0 = blockIdx.x * 128;
  const int wm = (wid >> 1) * 32, wn = (wid & 1) * 64;
  const int kq = (tid & 31) * 4;
  const int rbase = tid >> 5;
  {
    f32x4 raw[8];
    const f32x4 zz = {};
#pragma unroll
    for (int it = 0; it < 8; ++it) {
      int grow = row0 + it * 16 + rbase;
      raw[it] = (grow < NN) ? *(const f32x4*)(feat + (size_t)grow * 128 + kq) : zz;
    }
#pragma unroll
    for (int it = 0; it < 8; ++it) {
      int r = it * 16 + rbase;
      u16x4 p;
      p.x = f2b(raw[it].x); p.y = f2b(raw[it].y);
      p.z = f2b(raw[it].z); p.w = f2b(raw[it].w);
      *(u16x4*)&Alds[r * 128 + (((kq >> 3) ^ (r & 7)) << 3) + (kq & 7)] = p;
    }
  }
  __syncthreads();
  unsigned short* ep = &Epi[wid * 2560];
  {
    f32x4 acc[2][4] = {};
    mfma_128(Alds, W0, wm, wn, lane, acc);
    stats_to_lds(acc, Sred, wid, wn, lane);
    epi_store(acc, ep, row0, wm, wn, lane, H1);
  }
  __syncthreads();
  if (tid < 256) {
    int col = tid & 127;
    const float* sp = &Sred[(tid < 128) ? 0 : 512];
    float v = sp[col] + sp[128 + col] + sp[256 + col] + sp[384 + col];
    unsafeAtomicAdd(((tid < 128) ? cs0 : cq0) + col, v);
  }
  __syncthreads();                          // Sred reads done before layer-2 overwrites
  {
    f32x4 acc[2][4] = {};
    mfma_128(Alds, W2, wm, wn, lane, acc);  // Alds intact (Epi is separate)
    stats_to_lds(acc, Sred, wid, wn, lane);
    epi_store(acc, ep, row0, wm, wn, lane, H3);
  }
  __syncthreads();
  if (tid < 256) {
    int col = tid & 127;
    const float* sp = &Sred[(tid < 128) ? 0 : 512];
    float v = sp[col] + sp[128 + col] + sp[256 + col] + sp[384 + col];
    unsafeAtomicAdd(((tid < 128) ? cs2 : cq2) + col, v);
  }
}

// ---------- unified GEMM (r12): 512 thr, batched via blockIdx.y ----------
// MODE 1: A = bf16 row-major, transform relu(h*sc+sh); sc/sh from raw stats inline
// MODE 2: NCHK=2: ch0 = MODE1 transform on A; ch1 = swizzled bf16 (A2sw) via gl2lds
struct GArg {
  const void* A;
  const unsigned short* A2sw;
  const float* cs; const float* cq; const float* g; const float* be;
  const unsigned short* W;
  unsigned short* H;
  float* ocs; float* ocq;
};

template <int NCHK, int MODE>
__global__ __launch_bounds__(512, 4) void gemm_bn(GArg pa, GArg pb) {
  const GArg P = blockIdx.y ? pb : pa;
  __shared__ unsigned short Alds[16384];
  __shared__ unsigned short Epi[20480];
  __shared__ float Sred[1024];
  __shared__ float scs[128], shs[128];

  const int tid = threadIdx.x;
  if (tid < 128) {
    float mu = P.cs[tid] * (1.f / NN);
    float var = P.cq[tid] * (1.f / NN) - mu * mu;
    float s = P.g[tid] * rsqrtf(fmaxf(var, 0.f) + 1e-5f);
    scs[tid] = s;
    shs[tid] = P.be[tid] - mu * s;
  }
  __syncthreads();
  const int lane = tid & 63, wid = tid >> 6;
  const int row0 = blockIdx.x * 128;
  const int wm = (wid >> 1) * 32, wn = (wid & 1) * 64;
  const int kq = (tid & 31) * 4;
  const int rbase = tid >> 5;
  const f32x4 scv = *(const f32x4*)&scs[kq];
  const f32x4 shv = *(const f32x4*)&shs[kq];

  f32x4 acc[2][4] = {};
#pragma unroll
  for (int ch = 0; ch < NCHK; ++ch) {
    if (ch) __syncthreads();
    if (MODE == 2 && ch == 1) {
#pragma unroll
      for (int j = 0; j < 4; ++j) {
        int u = (wid * 4 + j) * 64 + lane;
        gl2lds(P.A2sw + (size_t)blockIdx.x * 16384 + (size_t)u * 8,
               &Alds[(wid * 4 + j) * 512]);
      }
    } else {
      u16x4 raw[8];
      const u16x4 zz = {};
#pragma unroll
      for (int it = 0; it < 8; ++it) {
        int grow = row0 + it * 16 + rbase;
        raw[it] = (grow < NN) ? *(const u16x4*)((const unsigned short*)P.A + (size_t)grow * 128 + kq)
                              : zz;
      }
#pragma unroll
      for (int it = 0; it < 8; ++it) {
        int r = it * 16 + rbase;
        bool ok = (row0 + r) < NN;
        float v0 = fmaxf(b2f(raw[it].x) * scv.x + shv.x, 0.f);
        float v1 = fmaxf(b2f(raw[it].y) * scv.y + shv.y, 0.f);
        float v2 = fmaxf(b2f(raw[it].z) * scv.z + shv.z, 0.f);
        float v3 = fmaxf(b2f(raw[it].w) * scv.w + shv.w, 0.f);
        u16x4 p;
        p.x = ok ? f2b(v0) : (unsigned short)0;
        p.y = ok ? f2b(v1) : (unsigned short)0;
        p.z = ok ? f2b(v2) : (unsigned short)0;
        p.w = ok ? f2b(v3) : (unsigned short)0;
        *(u16x4*)&Alds[r * 128 + (((kq >> 3) ^ (r & 7)) << 3) + (kq & 7)] = p;
      }
    }
    __syncthreads();
    mfma_128(Alds, P.W + ch * 16384, wm, wn, lane, acc);
  }
  stats_to_lds(acc, Sred, wid, wn, lane);
  epi_store(acc, &Epi[wid * 2560], row0, wm, wn, lane, P.H);
  __syncthreads();
  if (tid < 256) {
    int col = tid & 127;
    const float* sp = &Sred[(tid < 128) ? 0 : 512];
    float v = sp[col] + sp[128 + col] + sp[256 + col] + sp[384 + col];
    unsafeAtomicAdd(((tid < 128) ? P.ocs : P.ocq) + col, v);
  }
}

// ---------- CSR build: histogram, unordered block allocation, edge-id scatter ----------
__global__ __launch_bounds__(256) void hist_slot(const int* __restrict__ dst,
                                                 int* __restrict__ deg, int* __restrict__ slot) {
  int e = blockIdx.x * 256 + threadIdx.x;
  if (e < EE) slot[e] = atomicAdd(&deg[dst[e]], 1);
}

__global__ __launch_bounds__(256) void alloc_rows(const int* __restrict__ deg,
                                                  int* __restrict__ counter,
                                                  int* __restrict__ row_ptr) {
  __shared__ int tmp[256];
  __shared__ int base_s;
  int i = blockIdx.x * 256 + threadIdx.x;
  int t = threadIdx.x;
  int v = (i < NN) ? deg[i] : 0;
  tmp[t] = v;
  __syncthreads();
  for (int s = 1; s < 256; s <<= 1) {
    int a = (t >= s) ? tmp[t - s] : 0;
    __syncthreads();
    tmp[t] += a;
    __syncthreads();
  }
  if (t == 255) base_s = atomicAdd(counter, tmp[255]);
  __syncthreads();
  if (i < NN) row_ptr[i] = base_s + tmp[t] - v;
}

__global__ __launch_bounds__(256) void scatter_ids(const int* __restrict__ src,
                                                   const int* __restrict__ dst,
                                                   const int* __restrict__ row_ptr,
                                                   const int* __restrict__ slot,
                                                   int* __restrict__ csr_src) {
  int e = blockIdx.x * 256 + threadIdx.x;
  if (e < EE) csr_src[row_ptr[dst[e]] + slot[e]] = src[e];
}

// ---------- gather + mean: scalarized CSR walk, 8-deep pipeline ----------
__global__ __launch_bounds__(256) void gather_mean(
    const unsigned short* __restrict__ h2, const float* __restrict__ csIn,
    const float* __restrict__ cqIn, const float* __restrict__ g,
    const float* __restrict__ beta, const int* __restrict__ csr_src,
    const int* __restrict__ row_ptr, const int* __restrict__ deg,
    unsigned short* __restrict__ mean_sw) {
  const int lane = threadIdx.x & 63;
  const int node = (blockIdx.x << 2) + (threadIdx.x >> 6);
  if (node >= 100096) return;
  const int c0 = lane * 2;
  float mu0 = csIn[c0] * (1.f / NN), mu1 = csIn[c0 + 1] * (1.f / NN);
  float va0 = cqIn[c0] * (1.f / NN) - mu0 * mu0, va1 = cqIn[c0 + 1] * (1.f / NN) - mu1 * mu1;
  float s0 = g[c0] * rsqrtf(fmaxf(va0, 0.f) + 1e-5f);
  float s1 = g[c0 + 1] * rsqrtf(fmaxf(va1, 0.f) + 1e-5f);
  float t0 = beta[c0] - mu0 * s0, t1 = beta[c0 + 1] - mu1 * s1;
  float a0 = 0.f, a1 = 0.f, rc = 0.f;
  if (node < NN) {
    // wave-uniform CSR walk: force SGPR so index fetches use the scalar pipe
    const int beg = __builtin_amdgcn_readfirstlane(row_ptr[node]);
    const int d = __builtin_amdgcn_readfirstlane(deg[node]);
    const int end = beg + d;
    int e = beg;
    for (; e + 8 <= end; e += 8) {
      int ix[8];
#pragma unroll
      for (int k = 0; k < 8; ++k) ix[k] = csr_src[e + k];
      unsigned u[8];
#pragma unroll
      for (int k = 0; k < 8; ++k) u[k] = *(const unsigned*)(h2 + (size_t)ix[k] * 128 + c0);
#pragma unroll
      for (int k = 0; k < 8; ++k) {
        a0 += fmaxf(b2f((unsigned short)u[k]) * s0 + t0, 0.f);
        a1 += fmaxf(b2f((unsigned short)(u[k] >> 16)) * s1 + t1, 0.f);
      }
    }
    if (e + 4 <= end) {
      int ix[4];
#pragma unroll
      for (int k = 0; k < 4; ++k) ix[k] = csr_src[e + k];
      unsigned u[4];
#pragma unroll
      for (int k = 0; k < 4; ++k) u[k] = *(const unsigned*)(h2 + (size_t)ix[k] * 128 + c0);
#pragma unroll
      for (int k = 0; k < 4; ++k) {
        a0 += fmaxf(b2f((unsigned short)u[k]) * s0 + t0, 0.f);
        a1 += fmaxf(b2f((unsigned short)(u[k] >> 16)) * s1 + t1, 0.f);
      }
      e += 4;
    }
    if (e + 2 <= end) {
      int n0 = csr_src[e], n1 = csr_src[e + 1];
      unsigned u0 = *(const unsigned*)(h2 + (size_t)n0 * 128 + c0);
      unsigned u1 = *(const unsigned*)(h2 + (size_t)n1 * 128 + c0);
      a0 += fmaxf(b2f((unsigned short)u0) * s0 + t0, 0.f);
      a1 += fmaxf(b2f((unsigned short)(u0 >> 16)) * s1 + t1, 0.f);
      a0 += fmaxf(b2f((unsigned short)u1) * s0 + t0, 0.f);
      a1 += fmaxf(b2f((unsigned short)(u1 >> 16)) * s1 + t1, 0.f);
      e += 2;
    }
    if (e < end) {
      int n0 = csr_src[e];
      unsigned u0 = *(const unsigned*)(h2 + (size_t)n0 * 128 + c0);
      a0 += fmaxf(b2f((unsigned short)u0) * s0 + t0, 0.f);
      a1 += fmaxf(b2f((unsigned short)(u0 >> 16)) * s1 + t1, 0.f);
    }
    rc = (d > 0) ? 1.f / (float)d : 0.f;
  }
  // swizzled write matching gl2lds consumption
  int r = node & 127, t = node >> 7;
  int kk = (lane >> 2) ^ (r & 7);
  unsigned out = ((unsigned)f2b(a1 * rc) << 16) | (unsigned)f2b(a0 * rc);
  *(unsigned*)(mean_sw + (size_t)(t * 2048 + r * 16 + kk) * 8 + (lane & 3) * 2) = out;
}

// ---------- final normalize -> fp32 out (inline stats) ----------
__global__ __launch_bounds__(256) void norm_out(
    const unsigned short* __restrict__ h, const float* __restrict__ csIn,
    const float* __restrict__ cqIn, const float* __restrict__ g,
    const float* __restrict__ beta, float* __restrict__ out) {
  __shared__ float scs[128], shs[128];
  const int tid = threadIdx.x;
  if (tid < 128) {
    float mu = csIn[tid] * (1.f / NN);
    float var = cqIn[tid] * (1.f / NN) - mu * mu;
    float s = g[tid] * rsqrtf(fmaxf(var, 0.f) + 1e-5f);
    scs[tid] = s;
    shs[tid] = beta[tid] - mu * s;
  }
  __syncthreads();
  size_t e = ((size_t)blockIdx.x * 256 + tid) * 8;
  u16x8 v = *(const u16x8*)(h + e);
  int cb = (int)(e & 127);
  f32x4 sA = *(const f32x4*)&scs[cb], sB = *(const f32x4*)&scs[cb + 4];
  f32x4 tA = *(const f32x4*)&shs[cb], tB = *(const f32x4*)&shs[cb + 4];
  f32x4 o0, o1;
  o0.x = fmaxf(b2f(v[0]) * sA.x + tA.x, 0.f);
  o0.y = fmaxf(b2f(v[1]) * sA.y + tA.y, 0.f);
  o0.z = fmaxf(b2f(v[2]) * sA.z + tA.z, 0.f);
  o0.w = fmaxf(b2f(v[3]) * sA.w + tA.w, 0.f);
  o1.x = fmaxf(b2f(v[4]) * sB.x + tB.x, 0.f);
  o1.y = fmaxf(b2f(v[5]) * sB.y + tB.y, 0.f);
  o1.z = fmaxf(b2f(v[6]) * sB.z + tB.z, 0.f);
  o1.w = fmaxf(b2f(v[7]) * sB.w + tB.w, 0.f);
  *(f32x4*)(out + e) = o0;
  *(f32x4*)(out + e + 4) = o1;
}

extern "C" void kernel_launch(void* const* d_in, const int* in_sizes, int n_in,
                              void* d_out, int out_size, void* d_ws, size_t ws_size,
                              hipStream_t stream) {
  (void)in_sizes; (void)n_in; (void)out_size; (void)ws_size;
  const float* feat = (const float*)d_in[0];
  const int* src = (const int*)d_in[1];
  const int* dst = (const int*)d_in[2];
  const float* aW1 = (const float*)d_in[3];
  const float* aW2 = (const float*)d_in[4];
  const float* sW1 = (const float*)d_in[5];
  const float* sW2 = (const float*)d_in[6];
  const float* cW1 = (const float*)d_in[7];
  const float* cW2 = (const float*)d_in[8];
  // layer order: 0=aggr1 1=aggr2 2=self1 3=self2 4=comb1 5=comb2
  const float* g[6] = {(const float*)d_in[10], (const float*)d_in[13],
                       (const float*)d_in[16], (const float*)d_in[19],
                       (const float*)d_in[22], (const float*)d_in[25]};
  const float* be[6] = {(const float*)d_in[11], (const float*)d_in[14],
                        (const float*)d_in[17], (const float*)d_in[20],
                        (const float*)d_in[23], (const float*)d_in[26]};

  char* ws = (char*)d_ws;
  const size_t S = 25624576;                                   // 782 tiles * 32768 B
  unsigned short* WA = (unsigned short*)ws;                    // h1 / mean_sw
  unsigned short* WB = (unsigned short*)(ws + S);              // h2 / h6
  unsigned short* WC = (unsigned short*)(ws + 2 * S);          // h3 / h5
  int* row_ptr = (int*)(ws + 76873728);                        // 400,128 B
  int* deg = (int*)(ws + 77273856);                            // 400,000 B
  float* stats = (float*)(ws + 77673856);                      // 12,288 B (has spare slots)
  int* slot = (int*)(ws + 77686144);                           // 2,560,000 B
  int* csr_src = (int*)(ws + 80248192);                        // 2,560,000 B
  unsigned short* wt = (unsigned short*)(ws + 82808192);       // 229,376 B
  float* outF = (float*)d_out;
  unsigned short* h4 = (unsigned short*)d_out;                 // h4 parked in d_out bytes

  float* CS[6]; float* CQ[6];
  for (int L = 0; L < 6; ++L) {
    CS[L] = stats + L * 512;
    CQ[L] = stats + L * 512 + 128;
  }
  int* counter = (int*)(stats + 256);                          // spare slot, covered by memset

  hipMemsetAsync(deg, 0, 412288, stream);                      // deg + stats (incl. counter)
  prep_wt<<<112, 256, 0, stream>>>(aW1, aW2, sW1, sW2, cW1, cW2, wt);

  // CSR build: histogram -> unordered block allocation -> id scatter
  hist_slot<<<2500, 256, 0, stream>>>(dst, deg, slot);
  alloc_rows<<<391, 256, 0, stream>>>(deg, counter, row_ptr);
  scatter_ids<<<2500, 256, 0, stream>>>(src, dst, row_ptr, slot, csr_src);

  // G1: dual-output — one feat read, L1 -> h1 (WA), L3 -> h3 (WC)
  gemm_dual<<<782, 512, 0, stream>>>(feat, wt + 0 * 16384, wt + 2 * 16384,
                                     WA, WC, CS[0], CQ[0], CS[2], CQ[2]);
  GArg a{}, b{};
  // G2: L2+L4 batched (A = h1 / h3, MODE1)
  a = {WA, nullptr, CS[0], CQ[0], g[0], be[0], wt + 1 * 16384, WB, CS[1], CQ[1]};
  b = {WC, nullptr, CS[2], CQ[2], g[2], be[2], wt + 3 * 16384, h4, CS[3], CQ[3]};
  gemm_bn<1, 1><<<dim3(782, 2), 512, 0, stream>>>(a, b);
  // gather: mean of n(h2[src]) per dst -> WA (swizzled; h1 dead)
  gather_mean<<<25024, 256, 0, stream>>>(WB, CS[1], CQ[1], g[1], be[1],
                                         csr_src, row_ptr, deg, WA);
  // G3: L5 = [n(h4) | mean] -> h5 (WC; h3 dead)
  a = {h4, WA, CS[3], CQ[3], g[3], be[3], wt + 4 * 16384, WC, CS[4], CQ[4]};
  gemm_bn<2, 2><<<dim3(782, 1), 512, 0, stream>>>(a, a);
  // G4: L6 = n(h5) -> h6 (WB; h2 dead)
  a = {WC, nullptr, CS[4], CQ[4], g[4], be[4], wt + 6 * 16384, WB, CS[5], CQ[5]};
  gemm_bn<1, 1><<<dim3(782, 1), 512, 0, stream>>>(a, a);
  // final normalize -> fp32 out
  norm_out<<<6250, 256, 0, stream>>>(WB, CS[5], CQ[5], g[5], be[5], outF);
}